// Round 4
// baseline (116.120 us; speedup 1.0000x reference)
//
#include <hip/hip_runtime.h>

#define DIM 64
#define ROWS 128         // rows per block (kernel 1): 4 waves x 2 tiles x 16
#define LROW 72          // sWt padded row stride (shorts): 144 B, 16B-aligned frags
#define EPAD 72          // epilogue padded row stride (shorts)

// gfx950 builtins (cvt_pkrtz / fdot2 / mfma_*_f16) use __fp16 ext-vectors.
typedef __attribute__((ext_vector_type(8))) __fp16 half8;
typedef __attribute__((ext_vector_type(2))) __fp16 half2v;
typedef __attribute__((ext_vector_type(4))) float f32x4;

__device__ __forceinline__ unsigned int pk2(float a, float b) {
    half2v h = __builtin_amdgcn_cvt_pkrtz(a, b);   // v_cvt_pkrtz_f16_f32
    return __builtin_bit_cast(unsigned int, h);
}

__device__ __forceinline__ float dot8_f16(uint4 a, uint4 b) {
#if __has_builtin(__builtin_amdgcn_fdot2)
    half2v ax = __builtin_bit_cast(half2v, a.x), bx = __builtin_bit_cast(half2v, b.x);
    half2v ay = __builtin_bit_cast(half2v, a.y), by = __builtin_bit_cast(half2v, b.y);
    half2v az = __builtin_bit_cast(half2v, a.z), bz = __builtin_bit_cast(half2v, b.z);
    half2v aw = __builtin_bit_cast(half2v, a.w), bw = __builtin_bit_cast(half2v, b.w);
    float p0 = __builtin_amdgcn_fdot2(ax, bx, 0.f, false);
    p0 = __builtin_amdgcn_fdot2(ay, by, p0, false);
    float p1 = __builtin_amdgcn_fdot2(az, bz, 0.f, false);
    p1 = __builtin_amdgcn_fdot2(aw, bw, p1, false);
    return p0 + p1;
#else
    half2v ah[4] = {__builtin_bit_cast(half2v, a.x), __builtin_bit_cast(half2v, a.y),
                    __builtin_bit_cast(half2v, a.z), __builtin_bit_cast(half2v, a.w)};
    half2v bh[4] = {__builtin_bit_cast(half2v, b.x), __builtin_bit_cast(half2v, b.y),
                    __builtin_bit_cast(half2v, b.z), __builtin_bit_cast(half2v, b.w)};
    float p = 0.f;
#pragma unroll
    for (int i = 0; i < 4; ++i) {
        p = fmaf((float)ah[i][0], (float)bh[i][0], p);
        p = fmaf((float)ah[i][1], (float)bh[i][1], p);
    }
    return p;
#endif
}

__device__ __forceinline__ float red8(float p) {
    p += __shfl_xor(p, 1);
    p += __shfl_xor(p, 2);
    p += __shfl_xor(p, 4);
    return p;
}

// Kernel 1 (v6): zW = z @ W via f16 MFMA; tables emitted as f16.
// vs r2: all 8 z float4-loads (both row-tiles) issued BEFORE any packing,
// so HBM latency is exposed once (8-deep MLP) instead of twice.
__global__ __launch_bounds__(256) void zw_gemm_mfma_kernel(
    const float* __restrict__ z, const float* __restrict__ W,
    unsigned short* __restrict__ zw_h, unsigned short* __restrict__ z_h,
    int n_nodes) {
    __shared__ unsigned short sWt[DIM * LROW];       // W^T f16: sWt[n][k]
    __shared__ unsigned short sEpi[4 * 16 * EPAD];   // per-wave epilogue slab

    const int tid  = threadIdx.x;
    const int wave = tid >> 6;
    const int lane = tid & 63;
    const int m    = lane & 15;
    const int quad = lane >> 4;
    const int rowBase = blockIdx.x * ROWS;

    // ---- stage W transposed as f16: sWt[n*LROW + k] = f16(W[k*64+n]) ----
    for (int f = tid; f < DIM * DIM; f += 256) {
        const int n = f & 63;        // fastest -> coalesced global read
        const int k = f >> 6;
        sWt[n * LROW + k] = __builtin_bit_cast(unsigned short, (__fp16)W[f]);
    }

    // ---- A-fragment loads for BOTH row-tiles issued up-front (8 float4s) ----
    float4 v[2][4];
    int rowv[2];
#pragma unroll
    for (int tt = 0; tt < 2; ++tt) {
        const int row = rowBase + wave * 32 + tt * 16 + m;
        rowv[tt] = row;
        const int rc = row < n_nodes ? row : n_nodes - 1;   // clamp: always valid
        const float* zr = z + (size_t)rc * DIM + quad * 8;
        v[tt][0] = *(const float4*)(zr);
        v[tt][1] = *(const float4*)(zr + 4);
        v[tt][2] = *(const float4*)(zr + 32);
        v[tt][3] = *(const float4*)(zr + 36);
    }

    // ---- pack to f16 fragments; emit f16 copy of z from the same registers ----
    half8 a0[2], a1[2];
#pragma unroll
    for (int tt = 0; tt < 2; ++tt) {
        uint4 pa, pb;
        pa.x = pk2(v[tt][0].x, v[tt][0].y); pa.y = pk2(v[tt][0].z, v[tt][0].w);
        pa.z = pk2(v[tt][1].x, v[tt][1].y); pa.w = pk2(v[tt][1].z, v[tt][1].w);
        pb.x = pk2(v[tt][2].x, v[tt][2].y); pb.y = pk2(v[tt][2].z, v[tt][2].w);
        pb.z = pk2(v[tt][3].x, v[tt][3].y); pb.w = pk2(v[tt][3].z, v[tt][3].w);
        a0[tt] = __builtin_bit_cast(half8, pa);
        a1[tt] = __builtin_bit_cast(half8, pb);
        if (rowv[tt] < n_nodes) {
            *(uint4*)(z_h + (size_t)rowv[tt] * DIM + quad * 8)      = pa;
            *(uint4*)(z_h + (size_t)rowv[tt] * DIM + 32 + quad * 8) = pb;
        }
    }
    __syncthreads();   // sWt ready (the ONLY barrier)

    // ---- B-fragments once, shared across both row-tiles ----
    half8 b0[4], b1[4];
#pragma unroll
    for (int t = 0; t < 4; ++t) {
        const unsigned short* bBase = &sWt[(t * 16 + m) * LROW + quad * 8];
        b0[t] = *(const half8*)(bBase);
        b1[t] = *(const half8*)(bBase + 32);
    }

    unsigned short* ep = &sEpi[wave * 16 * EPAD];
#pragma unroll
    for (int tt = 0; tt < 2; ++tt) {
#pragma unroll
        for (int t = 0; t < 4; ++t) {
            f32x4 c = {0.f, 0.f, 0.f, 0.f};
            c = __builtin_amdgcn_mfma_f32_16x16x32_f16(a0[tt], b0[t], c, 0, 0, 0);
            c = __builtin_amdgcn_mfma_f32_16x16x32_f16(a1[tt], b1[t], c, 0, 0, 0);
#pragma unroll
            for (int r = 0; r < 4; ++r) {
                // C/D: col = t*16+m, row = quad*4+r
                ep[(quad * 4 + r) * EPAD + t * 16 + m] =
                    __builtin_bit_cast(unsigned short, (__fp16)c[r]);
            }
        }
        // wave-private slab: same-wave LDS ordering suffices, no barrier
        const int r = lane >> 2;   // 0..15: local row
        const int s = lane & 3;
        const int grow = rowBase + wave * 32 + tt * 16 + r;
#pragma unroll
        for (int h = 0; h < 2; ++h) {
            const int seg = h * 4 + s;   // 0..7: 8-short (16B) segment
            if (grow < n_nodes) {
                uint4 vv = *(const uint4*)(&ep[r * EPAD + seg * 8]);
                *(uint4*)(zw_h + (size_t)grow * DIM + seg * 8) = vv;
            }
        }
    }
}

// Kernel 2: 4 edges per 8-lane group; f16 rows, dot via v_dot2_f32_f16.
// Byte-identical in behavior to the round-2 version (proven passing).
__global__ __launch_bounds__(256) void edge_score_f16_kernel(
    const unsigned short* __restrict__ zw_h, const unsigned short* __restrict__ z_h,
    const int* __restrict__ edge_index, const float* __restrict__ bias,
    float* __restrict__ out, int n_edges) {
    const int tid = blockIdx.x * 256 + threadIdx.x;
    const int group = tid >> 3;
    const int sub = tid & 7;
    const int e0 = group * 4;
    if (e0 >= n_edges) return;

    const float bias0 = bias[0];

    if (e0 + 3 < n_edges) {
        int4 srcs = *(const int4*)(edge_index + e0);
        int4 dsts = *(const int4*)(edge_index + n_edges + e0);

        uint4 a0 = ((const uint4*)(zw_h + (size_t)srcs.x * DIM))[sub];
        uint4 a1 = ((const uint4*)(zw_h + (size_t)srcs.y * DIM))[sub];
        uint4 a2 = ((const uint4*)(zw_h + (size_t)srcs.z * DIM))[sub];
        uint4 a3 = ((const uint4*)(zw_h + (size_t)srcs.w * DIM))[sub];
        uint4 b0 = ((const uint4*)(z_h + (size_t)dsts.x * DIM))[sub];
        uint4 b1 = ((const uint4*)(z_h + (size_t)dsts.y * DIM))[sub];
        uint4 b2 = ((const uint4*)(z_h + (size_t)dsts.z * DIM))[sub];
        uint4 b3 = ((const uint4*)(z_h + (size_t)dsts.w * DIM))[sub];

        float p0 = red8(dot8_f16(a0, b0));
        float p1 = red8(dot8_f16(a1, b1));
        float p2 = red8(dot8_f16(a2, b2));
        float p3 = red8(dot8_f16(a3, b3));

        float v = (sub & 1) ? ((sub & 2) ? p3 : p1) : ((sub & 2) ? p2 : p0);
        if (sub < 4) out[e0 + sub] = v + bias0;
    } else {
        for (int e = e0; e < n_edges; ++e) {
            const int src = edge_index[e];
            const int dst = edge_index[n_edges + e];
            uint4 a = ((const uint4*)(zw_h + (size_t)src * DIM))[sub];
            uint4 b = ((const uint4*)(z_h + (size_t)dst * DIM))[sub];
            float p = red8(dot8_f16(a, b));
            if (sub == 0) out[e] = p + bias0;
        }
    }
}

extern "C" void kernel_launch(void* const* d_in, const int* in_sizes, int n_in,
                              void* d_out, int out_size, void* d_ws, size_t ws_size,
                              hipStream_t stream) {
    const float* z          = (const float*)d_in[0];
    const int*   edge_index = (const int*)d_in[1];
    const float* W          = (const float*)d_in[2];
    const float* bias       = (const float*)d_in[3];
    float* out = (float*)d_out;

    const int n_nodes = in_sizes[0] / DIM;
    const int n_edges = in_sizes[1] / 2;

    unsigned short* zw_h = (unsigned short*)d_ws;                 // 12.8 MB (f16)
    unsigned short* z_h  = zw_h + (size_t)n_nodes * DIM;          // 12.8 MB (f16)

    const int gemm_blocks = (n_nodes + ROWS - 1) / ROWS;
    zw_gemm_mfma_kernel<<<gemm_blocks, 256, 0, stream>>>(z, W, zw_h, z_h, n_nodes);

    const int edge_blocks = (n_edges + 127) / 128;
    edge_score_f16_kernel<<<edge_blocks, 256, 0, stream>>>(zw_h, z_h, edge_index,
                                                           bias, out, n_edges);
}

// Round 5
// 113.829 us; speedup vs baseline: 1.0201x; 1.0201x over previous
//
#include <hip/hip_runtime.h>

#define DIM 64
#define ROWS 128         // rows per block (kernel 1): 4 waves x 2 tiles x 16
#define LROW 72          // sWt padded row stride (shorts): 144 B, 16B-aligned frags
#define EPAD 72          // epilogue padded row stride (shorts)

// gfx950 builtins (cvt_pkrtz / fdot2 / mfma_*_f16) use __fp16 ext-vectors.
typedef __attribute__((ext_vector_type(8))) __fp16 half8;
typedef __attribute__((ext_vector_type(2))) __fp16 half2v;
typedef __attribute__((ext_vector_type(4))) float f32x4;

__device__ __forceinline__ unsigned int pk2(float a, float b) {
    half2v h = __builtin_amdgcn_cvt_pkrtz(a, b);   // v_cvt_pkrtz_f16_f32
    return __builtin_bit_cast(unsigned int, h);
}

__device__ __forceinline__ float dot8_f16(uint4 a, uint4 b) {
#if __has_builtin(__builtin_amdgcn_fdot2)
    half2v ax = __builtin_bit_cast(half2v, a.x), bx = __builtin_bit_cast(half2v, b.x);
    half2v ay = __builtin_bit_cast(half2v, a.y), by = __builtin_bit_cast(half2v, b.y);
    half2v az = __builtin_bit_cast(half2v, a.z), bz = __builtin_bit_cast(half2v, b.z);
    half2v aw = __builtin_bit_cast(half2v, a.w), bw = __builtin_bit_cast(half2v, b.w);
    float p0 = __builtin_amdgcn_fdot2(ax, bx, 0.f, false);
    p0 = __builtin_amdgcn_fdot2(ay, by, p0, false);
    float p1 = __builtin_amdgcn_fdot2(az, bz, 0.f, false);
    p1 = __builtin_amdgcn_fdot2(aw, bw, p1, false);
    return p0 + p1;
#else
    half2v ah[4] = {__builtin_bit_cast(half2v, a.x), __builtin_bit_cast(half2v, a.y),
                    __builtin_bit_cast(half2v, a.z), __builtin_bit_cast(half2v, a.w)};
    half2v bh[4] = {__builtin_bit_cast(half2v, b.x), __builtin_bit_cast(half2v, b.y),
                    __builtin_bit_cast(half2v, b.z), __builtin_bit_cast(half2v, b.w)};
    float p = 0.f;
#pragma unroll
    for (int i = 0; i < 4; ++i) {
        p = fmaf((float)ah[i][0], (float)bh[i][0], p);
        p = fmaf((float)ah[i][1], (float)bh[i][1], p);
    }
    return p;
#endif
}

__device__ __forceinline__ float red8(float p) {
    p += __shfl_xor(p, 1);
    p += __shfl_xor(p, 2);
    p += __shfl_xor(p, 4);
    return p;
}

// Kernel 1 (v6, unchanged from round 4 — proven passing).
__global__ __launch_bounds__(256) void zw_gemm_mfma_kernel(
    const float* __restrict__ z, const float* __restrict__ W,
    unsigned short* __restrict__ zw_h, unsigned short* __restrict__ z_h,
    int n_nodes) {
    __shared__ unsigned short sWt[DIM * LROW];       // W^T f16: sWt[n][k]
    __shared__ unsigned short sEpi[4 * 16 * EPAD];   // per-wave epilogue slab

    const int tid  = threadIdx.x;
    const int wave = tid >> 6;
    const int lane = tid & 63;
    const int m    = lane & 15;
    const int quad = lane >> 4;
    const int rowBase = blockIdx.x * ROWS;

    // ---- stage W transposed as f16: sWt[n*LROW + k] = f16(W[k*64+n]) ----
    for (int f = tid; f < DIM * DIM; f += 256) {
        const int n = f & 63;        // fastest -> coalesced global read
        const int k = f >> 6;
        sWt[n * LROW + k] = __builtin_bit_cast(unsigned short, (__fp16)W[f]);
    }

    // ---- A-fragment loads for BOTH row-tiles issued up-front (8 float4s) ----
    float4 v[2][4];
    int rowv[2];
#pragma unroll
    for (int tt = 0; tt < 2; ++tt) {
        const int row = rowBase + wave * 32 + tt * 16 + m;
        rowv[tt] = row;
        const int rc = row < n_nodes ? row : n_nodes - 1;   // clamp: always valid
        const float* zr = z + (size_t)rc * DIM + quad * 8;
        v[tt][0] = *(const float4*)(zr);
        v[tt][1] = *(const float4*)(zr + 4);
        v[tt][2] = *(const float4*)(zr + 32);
        v[tt][3] = *(const float4*)(zr + 36);
    }

    // ---- pack to f16 fragments; emit f16 copy of z from the same registers ----
    half8 a0[2], a1[2];
#pragma unroll
    for (int tt = 0; tt < 2; ++tt) {
        uint4 pa, pb;
        pa.x = pk2(v[tt][0].x, v[tt][0].y); pa.y = pk2(v[tt][0].z, v[tt][0].w);
        pa.z = pk2(v[tt][1].x, v[tt][1].y); pa.w = pk2(v[tt][1].z, v[tt][1].w);
        pb.x = pk2(v[tt][2].x, v[tt][2].y); pb.y = pk2(v[tt][2].z, v[tt][2].w);
        pb.z = pk2(v[tt][3].x, v[tt][3].y); pb.w = pk2(v[tt][3].z, v[tt][3].w);
        a0[tt] = __builtin_bit_cast(half8, pa);
        a1[tt] = __builtin_bit_cast(half8, pb);
        if (rowv[tt] < n_nodes) {
            *(uint4*)(z_h + (size_t)rowv[tt] * DIM + quad * 8)      = pa;
            *(uint4*)(z_h + (size_t)rowv[tt] * DIM + 32 + quad * 8) = pb;
        }
    }
    __syncthreads();   // sWt ready (the ONLY barrier)

    // ---- B-fragments once, shared across both row-tiles ----
    half8 b0[4], b1[4];
#pragma unroll
    for (int t = 0; t < 4; ++t) {
        const unsigned short* bBase = &sWt[(t * 16 + m) * LROW + quad * 8];
        b0[t] = *(const half8*)(bBase);
        b1[t] = *(const half8*)(bBase + 32);
    }

    unsigned short* ep = &sEpi[wave * 16 * EPAD];
#pragma unroll
    for (int tt = 0; tt < 2; ++tt) {
#pragma unroll
        for (int t = 0; t < 4; ++t) {
            f32x4 c = {0.f, 0.f, 0.f, 0.f};
            c = __builtin_amdgcn_mfma_f32_16x16x32_f16(a0[tt], b0[t], c, 0, 0, 0);
            c = __builtin_amdgcn_mfma_f32_16x16x32_f16(a1[tt], b1[t], c, 0, 0, 0);
#pragma unroll
            for (int r = 0; r < 4; ++r) {
                // C/D: col = t*16+m, row = quad*4+r
                ep[(quad * 4 + r) * EPAD + t * 16 + m] =
                    __builtin_bit_cast(unsigned short, (__fp16)c[r]);
            }
        }
        // wave-private slab: same-wave LDS ordering suffices, no barrier
        const int r = lane >> 2;   // 0..15: local row
        const int s = lane & 3;
        const int grow = rowBase + wave * 32 + tt * 16 + r;
#pragma unroll
        for (int h = 0; h < 2; ++h) {
            const int seg = h * 4 + s;   // 0..7: 8-short (16B) segment
            if (grow < n_nodes) {
                uint4 vv = *(const uint4*)(&ep[r * EPAD + seg * 8]);
                *(uint4*)(zw_h + (size_t)grow * DIM + seg * 8) = vv;
            }
        }
    }
}

// Kernel 2 (v3): occupancy experiment — __launch_bounds__(256, 8) caps VGPR
// at 64 to get 8 waves/SIMD (vs est. 5-6), raising outstanding-gather capacity.
// Gather addressing switched to 32-bit byte offsets (tables span 12.8 MB) so
// the allocator can fit: 8 x uint offset (rematerializable) instead of
// 8 x 64-bit address pairs.
__global__ __launch_bounds__(256, 8) void edge_score_f16_kernel(
    const unsigned short* __restrict__ zw_h, const unsigned short* __restrict__ z_h,
    const int* __restrict__ edge_index, const float* __restrict__ bias,
    float* __restrict__ out, int n_edges) {
    const int tid = blockIdx.x * 256 + threadIdx.x;
    const int group = tid >> 3;
    const int sub = tid & 7;
    const int e0 = group * 4;
    if (e0 >= n_edges) return;

    const float bias0 = bias[0];

    if (e0 + 3 < n_edges) {
        int4 srcs = *(const int4*)(edge_index + e0);
        int4 dsts = *(const int4*)(edge_index + n_edges + e0);

        const char* zb = (const char*)zw_h;   // row = node * 128 bytes
        const char* hb = (const char*)z_h;
        const unsigned so = (unsigned)sub * 16u;

        uint4 a0 = *(const uint4*)(zb + (unsigned)srcs.x * 128u + so);
        uint4 a1 = *(const uint4*)(zb + (unsigned)srcs.y * 128u + so);
        uint4 a2 = *(const uint4*)(zb + (unsigned)srcs.z * 128u + so);
        uint4 a3 = *(const uint4*)(zb + (unsigned)srcs.w * 128u + so);
        uint4 b0 = *(const uint4*)(hb + (unsigned)dsts.x * 128u + so);
        uint4 b1 = *(const uint4*)(hb + (unsigned)dsts.y * 128u + so);
        uint4 b2 = *(const uint4*)(hb + (unsigned)dsts.z * 128u + so);
        uint4 b3 = *(const uint4*)(hb + (unsigned)dsts.w * 128u + so);

        float p0 = red8(dot8_f16(a0, b0));
        float p1 = red8(dot8_f16(a1, b1));
        float p2 = red8(dot8_f16(a2, b2));
        float p3 = red8(dot8_f16(a3, b3));

        float v = (sub & 1) ? ((sub & 2) ? p3 : p1) : ((sub & 2) ? p2 : p0);
        if (sub < 4) out[e0 + sub] = v + bias0;
    } else {
        for (int e = e0; e < n_edges; ++e) {
            const int src = edge_index[e];
            const int dst = edge_index[n_edges + e];
            uint4 a = *(const uint4*)((const char*)zw_h + (unsigned)src * 128u +
                                      (unsigned)sub * 16u);
            uint4 b = *(const uint4*)((const char*)z_h + (unsigned)dst * 128u +
                                      (unsigned)sub * 16u);
            float p = red8(dot8_f16(a, b));
            if (sub == 0) out[e] = p + bias0;
        }
    }
}

extern "C" void kernel_launch(void* const* d_in, const int* in_sizes, int n_in,
                              void* d_out, int out_size, void* d_ws, size_t ws_size,
                              hipStream_t stream) {
    const float* z          = (const float*)d_in[0];
    const int*   edge_index = (const int*)d_in[1];
    const float* W          = (const float*)d_in[2];
    const float* bias       = (const float*)d_in[3];
    float* out = (float*)d_out;

    const int n_nodes = in_sizes[0] / DIM;
    const int n_edges = in_sizes[1] / 2;

    unsigned short* zw_h = (unsigned short*)d_ws;                 // 12.8 MB (f16)
    unsigned short* z_h  = zw_h + (size_t)n_nodes * DIM;          // 12.8 MB (f16)

    const int gemm_blocks = (n_nodes + ROWS - 1) / ROWS;
    zw_gemm_mfma_kernel<<<gemm_blocks, 256, 0, stream>>>(z, W, zw_h, z_h, n_nodes);

    const int edge_blocks = (n_edges + 127) / 128;
    edge_score_f16_kernel<<<edge_blocks, 256, 0, stream>>>(zw_h, z_h, edge_index,
                                                           bias, out, n_edges);
}